// Round 12
// baseline (218.612 us; speedup 1.0000x reference)
//
#include <hip/hip_runtime.h>
#include <math.h>

#define L 4096
#define D 1024
#define H 16
#define KV 4
#define DH 64
// G = H/KV = 4

typedef __attribute__((ext_vector_type(8))) short bf16x8;
typedef __attribute__((ext_vector_type(4))) float f32x4;
typedef __attribute__((ext_vector_type(16))) float f32x16;
typedef __attribute__((ext_vector_type(2))) unsigned int u32x2;

static __device__ __forceinline__ unsigned short f2bf(float f) {
    unsigned u = __float_as_uint(f);
    u = (u + 0x7FFF + ((u >> 16) & 1)) >> 16;   // RNE
    return (unsigned short)u;
}

static __device__ __forceinline__ bf16x8 mk8(unsigned a, unsigned b, unsigned c, unsigned d) {
    union { unsigned u[4]; bf16x8 v; } x;
    x.u[0] = a; x.u[1] = b; x.u[2] = c; x.u[3] = d;
    return x.v;
}

#define EXP2F(x) __builtin_amdgcn_exp2f(x)
#define ZERO16 ((f32x16){0.f,0.f,0.f,0.f,0.f,0.f,0.f,0.f,0.f,0.f,0.f,0.f,0.f,0.f,0.f,0.f})

// async global->LDS, 16B per lane; dst must be wave-uniform base (HW: base + lane*16)
#define GLD16(src, dst) \
    __builtin_amdgcn_global_load_lds((__attribute__((address_space(1))) void*)(src), \
                                     (__attribute__((address_space(3))) void*)(dst), 16, 0, 0)

// ---------------------------------------------------------------------------
// prep: x fp32->bf16, and the four weight transposes (dst[n][k] bf16, K=1024).
// ---------------------------------------------------------------------------
__global__ __launch_bounds__(256) void prep_kernel(
        const float* __restrict__ x,  const float* __restrict__ Wq,
        const float* __restrict__ Wk, const float* __restrict__ Wv,
        const float* __restrict__ Wo,
        unsigned short* __restrict__ xb, unsigned short* __restrict__ WqkvT,
        unsigned short* __restrict__ WoT) {
    const int b = blockIdx.x, tid = threadIdx.x;
    if (b < 4096) {
        int i = (b * 256 + tid) * 4;
        float4 v = *(const float4*)&x[i];
        ushort4 o;
        o.x = f2bf(v.x); o.y = f2bf(v.y); o.z = f2bf(v.z); o.w = f2bf(v.w);
        *(ushort4*)&xb[i] = o;
        return;
    }
    __shared__ float t[32][33];
    const float* src; unsigned short* dst; int N, n0, k0;
    if (b < 5120)      { int tq = b - 4096; src = Wq; dst = WqkvT;                     N = 1024; n0 = (tq & 31) * 32; k0 = (tq >> 5) * 32; }
    else if (b < 5376) { int tq = b - 5120; src = Wk; dst = WqkvT + (size_t)1024*1024; N = 256;  n0 = (tq & 7)  * 32; k0 = (tq >> 3) * 32; }
    else if (b < 5632) { int tq = b - 5376; src = Wv; dst = WqkvT + (size_t)1280*1024; N = 256;  n0 = (tq & 7)  * 32; k0 = (tq >> 3) * 32; }
    else               { int tq = b - 5632; src = Wo; dst = WoT;                       N = 1024; n0 = (tq & 31) * 32; k0 = (tq >> 5) * 32; }
    const int tx = tid & 31, ty = tid >> 5;
    #pragma unroll
    for (int j = 0; j < 4; ++j)
        t[ty + 8 * j][tx] = src[(size_t)(k0 + ty + 8 * j) * N + n0 + tx];
    __syncthreads();
    #pragma unroll
    for (int j = 0; j < 4; ++j)
        dst[(size_t)(n0 + ty + 8 * j) * 1024 + k0 + tx] = f2bf(t[tx][ty + 8 * j]);
}

// ---------------------------------------------------------------------------
// bf16 MFMA GEMM (fp32 out) for the Wo projection. Tile 64x128, 512 blocks.
// ---------------------------------------------------------------------------
__global__ __launch_bounds__(256) void gemm_bf16(const unsigned short* __restrict__ A,
                                                 const unsigned short* __restrict__ BT,
                                                 float* __restrict__ C,
                                                 int M, int N, int K) {
    __shared__ unsigned short As[64 * 32];
    __shared__ unsigned short Bs[128 * 32];

    const int tid  = threadIdx.x;
    const int w    = tid >> 6;
    const int lane = tid & 63;
    const int c    = lane & 15;
    const int quad = lane >> 4;
    const int wy = w >> 1, wx = w & 1;
    const int row0 = blockIdx.y * 64;
    const int col0 = blockIdx.x * 128;

    const int ld_row = lane >> 2;
    const int ld_col = (lane & 3) * 8;

    f32x4 acc[2][4];
    #pragma unroll
    for (int mt = 0; mt < 2; ++mt)
        #pragma unroll
        for (int nt = 0; nt < 4; ++nt)
            acc[mt][nt] = (f32x4){0.f, 0.f, 0.f, 0.f};

    for (int k0 = 0; k0 < K; k0 += 32) {
        __syncthreads();
        GLD16(&A [(size_t)(row0 + w * 16 + ld_row)      * K + k0 + ld_col], &As[w * 512]);
        GLD16(&BT[(size_t)(col0 + w * 16 + ld_row)      * K + k0 + ld_col], &Bs[w * 512]);
        GLD16(&BT[(size_t)(col0 + w * 16 + 64 + ld_row) * K + k0 + ld_col], &Bs[w * 512 + 2048]);
        __syncthreads();

        bf16x8 af[2], bfr[4];
        #pragma unroll
        for (int mt = 0; mt < 2; ++mt)
            af[mt] = *(const bf16x8*)&As[(wy * 32 + mt * 16 + c) * 32 + quad * 8];
        #pragma unroll
        for (int nt = 0; nt < 4; ++nt)
            bfr[nt] = *(const bf16x8*)&Bs[(wx * 64 + nt * 16 + c) * 32 + quad * 8];

        #pragma unroll
        for (int mt = 0; mt < 2; ++mt)
            #pragma unroll
            for (int nt = 0; nt < 4; ++nt)
                acc[mt][nt] = __builtin_amdgcn_mfma_f32_16x16x32_bf16(af[mt], bfr[nt], acc[mt][nt], 0, 0, 0);
    }

    #pragma unroll
    for (int mt = 0; mt < 2; ++mt)
        #pragma unroll
        for (int nt = 0; nt < 4; ++nt)
            #pragma unroll
            for (int r = 0; r < 4; ++r)
                C[(size_t)(row0 + wy * 32 + mt * 16 + quad * 4 + r) * N
                  + col0 + wx * 64 + nt * 16 + c] = acc[mt][nt][r];
}

// ---------------------------------------------------------------------------
// Fused QKV GEMM + RoPE epilogue. Tile 64x128, grid (12,64) = 768 blocks.
// V is written TRANSPOSED (vbT[kv*DH+d][l], L-contiguous) so attention can
// stage V^T rows straight into LDS with global_load_lds (R4 epilogue,
// verified; adapted to the 64-row tile).
// ---------------------------------------------------------------------------
__global__ __launch_bounds__(256) void gemm_qkv_rope(
        const unsigned short* __restrict__ A,
        const unsigned short* __restrict__ BT,
        unsigned short* __restrict__ qb,
        unsigned short* __restrict__ kbuf,
        unsigned short* __restrict__ vbT) {
    __shared__ unsigned short As[64 * 32];
    __shared__ unsigned short Bs[128 * 32];

    const int tid  = threadIdx.x;
    const int w    = tid >> 6;
    const int lane = tid & 63;
    const int c    = lane & 15;
    const int quad = lane >> 4;
    const int wy = w >> 1, wx = w & 1;
    const int row0 = blockIdx.y * 64;
    const int col0 = blockIdx.x * 128;

    const int ld_row = lane >> 2;
    const int ld_col = (lane & 3) * 8;

    f32x4 acc[2][4];
    #pragma unroll
    for (int mt = 0; mt < 2; ++mt)
        #pragma unroll
        for (int nt = 0; nt < 4; ++nt)
            acc[mt][nt] = (f32x4){0.f, 0.f, 0.f, 0.f};

    for (int k0 = 0; k0 < 1024; k0 += 32) {
        __syncthreads();
        GLD16(&A [(size_t)(row0 + w * 16 + ld_row)      * 1024 + k0 + ld_col], &As[w * 512]);
        GLD16(&BT[(size_t)(col0 + w * 16 + ld_row)      * 1024 + k0 + ld_col], &Bs[w * 512]);
        GLD16(&BT[(size_t)(col0 + w * 16 + 64 + ld_row) * 1024 + k0 + ld_col], &Bs[w * 512 + 2048]);
        __syncthreads();

        bf16x8 af[2], bfr[4];
        #pragma unroll
        for (int mt = 0; mt < 2; ++mt)
            af[mt] = *(const bf16x8*)&As[(wy * 32 + mt * 16 + c) * 32 + quad * 8];
        #pragma unroll
        for (int nt = 0; nt < 4; ++nt)
            bfr[nt] = *(const bf16x8*)&Bs[(wx * 64 + nt * 16 + c) * 32 + quad * 8];

        #pragma unroll
        for (int mt = 0; mt < 2; ++mt)
            #pragma unroll
            for (int nt = 0; nt < 4; ++nt)
                acc[mt][nt] = __builtin_amdgcn_mfma_f32_16x16x32_bf16(af[mt], bfr[nt], acc[mt][nt], 0, 0, 0);
    }

    const int colb = col0 + wx * 64;
    if (colb < 1280) {
        unsigned short* dst; int hh, hstride; float scale;
        if (colb < 1024) { dst = qb;   hh = colb >> 6;          hstride = H;  scale = 0.18033688011112042f; }
        else             { dst = kbuf; hh = (colb - 1024) >> 6; hstride = KV; scale = 1.0f; }
        #pragma unroll
        for (int nt = 0; nt < 2; ++nt) {
            int d = nt * 16 + c;
            float invf = EXP2F((float)d * -0.4152410118609203f);
            #pragma unroll
            for (int mt = 0; mt < 2; ++mt)
                #pragma unroll
                for (int r = 0; r < 4; ++r) {
                    int l = row0 + wy * 32 + mt * 16 + quad * 4 + r;
                    float ang = (float)l * invf;
                    float sn = __sinf(ang), cs = __cosf(ang);
                    float x1 = acc[mt][nt][r], x2 = acc[mt][nt + 2][r];
                    dst[((size_t)l * hstride + hh) * DH + d]      = f2bf((x1 * cs - x2 * sn) * scale);
                    dst[((size_t)l * hstride + hh) * DH + d + 32] = f2bf((x2 * cs + x1 * sn) * scale);
                }
        }
    } else {
        // V^T: vbT[(vh*DH + d) * L + l], packed 4 contiguous l per store
        int vh = (colb - 1280) >> 6;
        #pragma unroll
        for (int nt = 0; nt < 4; ++nt)
            #pragma unroll
            for (int mt = 0; mt < 2; ++mt) {
                int l = row0 + wy * 32 + mt * 16 + quad * 4;
                ushort4 o;
                o.x = f2bf(acc[mt][nt][0]); o.y = f2bf(acc[mt][nt][1]);
                o.z = f2bf(acc[mt][nt][2]); o.w = f2bf(acc[mt][nt][3]);
                *(ushort4*)&vbT[(size_t)(vh * DH + nt * 16 + c) * L + l] = o;
            }
    }
}

// ---------------------------------------------------------------------------
// MFMA attention, 32x32x16 — BARRIER-FREE main loop via WAVE-PRIVATE V tiles
// + counted vmcnt (T4). Grid (64, KV), 512 thr, 1 block/CU, 2 waves/SIMD.
// Wave w: head kv*4+(w&3), key-half g=w>>2, 64 q-rows, 32 iters of 64 keys.
//
// R11 counters: MfmaUtil 31 / VALUBusy 46 (incl. MFMA issue) -> ~50% of each
// iteration was barrier convoy + full vmcnt(0) drain. Fix: each wave stages
// its OWN [64 d][64 key] V^T tile from vbT via 8 coalesced GLD16/iter into a
// private 16 KB double-buffered LDS slice (8x16 = 128 KB), so no wave shares
// staged data -> no __syncthreads in the loop. Cross-iteration ordering is
// "s_waitcnt vmcnt(8)": issue next-tile GLD16s first, then wait until only
// those 8 newest remain -> prev V staging AND prev K prefetch drained, waves
// drift freely (anti-phase MFMA/VALU overlap across the 2 waves/SIMD).
// Staging is SKIPPED at it==31 so no GLD16 is in flight when the epilogue
// overlays waves 0-3's dead Vt slices with the fp32 partial buffer.
// XOR swizzle (chunk ^= d&7) folded into the per-lane SOURCE offset
// (LDS dest stays linear per G21); PV reads use the same XOR as R3/R11.
// Softmax fully in-register; rowsums = VALU adds on bf16-truncated values.
// NOTE (R2): plain loop body only — no [&] lambda (scratch catastrophe).
// NOTE (R10): 1024-thr blocks force a 64-VGPR binary; stay at 512 thr.
// ---------------------------------------------------------------------------
__global__ __attribute__((amdgpu_flat_work_group_size(512, 512), amdgpu_waves_per_eu(2)))
void attn_mfma_kernel(
        const unsigned short* __restrict__ qb,
        const unsigned short* __restrict__ kb,
        const unsigned short* __restrict__ vbT,
        unsigned short* __restrict__ ob) {
    __shared__ __align__(16) unsigned short Vt[8][2][64][64];  // 128 KB wave-private [wave][buf][d][key]
    __shared__ __align__(16) float Rs[8][2][32];               //   2 KB rowsums [wave][qt][q]

    const int tid  = threadIdx.x;
    const int w    = tid >> 6;        // 0..7
    const int lane = tid & 63;
    const int c32  = lane & 31;
    const int hi   = lane >> 5;
    const int g    = w >> 2;          // key group
    const int kv = blockIdx.y;
    const int h  = kv * 4 + (w & 3);
    const int q0 = blockIdx.x * 64;
    const int s_base = g * 2048;

    // ---- V staging (wave-private): slab s covers d-rows s*8..s*8+7; lane l
    // loads row r=l>>3, source chunk (l&7)^r (16B), lands at phys chunk l&7.
    const unsigned short* vbase = vbT + ((size_t)kv * DH) * L + s_base;
    const int lr = lane >> 3;
    const int laneoff = lr * L + (((lane & 7) ^ lr) << 3);
    unsigned short* VtW = &Vt[w][0][0][0];

    // Q B-frags: col=q=c32, k-elems d = kd*16 + hi*8 + j
    bf16x8 qf[2][4];
    {
        const unsigned short* qbase = qb + ((size_t)(q0 + c32) * H + h) * DH + hi * 8;
        #pragma unroll
        for (int qt = 0; qt < 2; ++qt)
            #pragma unroll
            for (int kd = 0; kd < 4; ++kd)
                qf[qt][kd] = *(const bf16x8*)&qbase[qt * 32 * H * DH + kd * 16];
    }

    f32x16 oacc[2][2];    // [qt][dt]: col=d=dt*32+c32, row=q=(r&3)+8(r>>2)+4hi
    #pragma unroll
    for (int qt = 0; qt < 2; ++qt)
        #pragma unroll
        for (int dt = 0; dt < 2; ++dt)
            oacc[qt][dt] = ZERO16;
    float rsum[2] = {0.f, 0.f};   // per-lane partial rowsum, q = qt*32 + c32

    const unsigned short* kbase = kb + ((size_t)(s_base + c32) * KV + kv) * DH + hi * 8;

    // ---- prologue: K tiles for iter 0; V iter 0 into buf 0 ----
    bf16x8 kf[2][4];   // [key-32-tile][kd]: row=key=c32, k-elems d = kd*16+hi*8+j
    #pragma unroll
    for (int a = 0; a < 2; ++a)
        #pragma unroll
        for (int kd = 0; kd < 4; ++kd)
            kf[a][kd] = *(const bf16x8*)&kbase[a * 32 * KV * DH + kd * 16];
    {
        const unsigned short* vs = vbase + laneoff;
        #pragma unroll
        for (int s = 0; s < 8; ++s)
            GLD16(vs + s * (8 * L), VtW + s * 512);
    }

    for (int it = 0; it < 32; ++it) {
        const int bufo = (it & 1) * 4096;    // elems; wave-private double buffer
        const int itn = (it + 1) & 31;

        // ---- issue next V staging (8 GLD16 into buf^1); skip at it==31 so
        //      nothing is in flight when the epilogue overlays LDS ----
        if (it != 31) {
            const unsigned short* vs = vbase + itn * 64 + laneoff;
            #pragma unroll
            for (int s = 0; s < 8; ++s)
                GLD16(vs + s * (8 * L), VtW + (bufo ^ 4096) + s * 512);
        }
        // ---- counted drain: allow only the 8 just-issued to remain; all
        //      older ops (prev V staging, prev K prefetch) complete ----
        asm volatile("s_waitcnt vmcnt(8)" ::: "memory");

        #pragma unroll
        for (int kt2 = 0; kt2 < 2; ++kt2) {
            bf16x8 pf[2][2];   // [qt][f]: PV A-frags, keys kt2*32 + f*16 + hi*8 + j
            #pragma unroll
            for (int qt = 0; qt < 2; ++qt) {
                // St = K @ Q^T (32x32, K-dim = DH via 4 chained MFMAs)
                f32x16 s = ZERO16;
                #pragma unroll
                for (int kd = 0; kd < 4; ++kd)
                    s = __builtin_amdgcn_mfma_f32_32x32x16_bf16(kf[kt2][kd], qf[qt][kd], s, 0, 0, 0);
                // exp2, truncate to bf16 domain (matches packed PV operand)
                float p[16];
                #pragma unroll
                for (int r = 0; r < 16; ++r)
                    p[r] = __uint_as_float(__float_as_uint(EXP2F(s[r])) & 0xFFFF0000u);
                // rowsum for q = qt*32+c32 over this lane's 16 keys
                float t0 = (p[0] + p[1]) + (p[2] + p[3]);
                float t1 = (p[4] + p[5]) + (p[6] + p[7]);
                float t2 = (p[8] + p[9]) + (p[10] + p[11]);
                float t3 = (p[12] + p[13]) + (p[14] + p[15]);
                rsum[qt] += (t0 + t1) + (t2 + t3);
                // pack key-pairs: u[i] = bf16(p[2i]) | bf16(p[2i+1])<<16
                unsigned u[8];
                #pragma unroll
                for (int i = 0; i < 8; ++i)
                    u[i] = __builtin_amdgcn_perm(__float_as_uint(p[2 * i + 1]),
                                                 __float_as_uint(p[2 * i]), 0x07060302u);
                // cross-half redistribute: swap(u0,u2)->slots{0,2}, swap(u1,u3)->slots{1,3}
                #pragma unroll
                for (int f = 0; f < 2; ++f) {
                    u32x2 e0 = __builtin_amdgcn_permlane32_swap(u[4 * f + 0], u[4 * f + 2], false, false);
                    u32x2 e1 = __builtin_amdgcn_permlane32_swap(u[4 * f + 1], u[4 * f + 3], false, false);
                    pf[qt][f] = mk8(e0.x, e1.x, e0.y, e1.y);
                }
            }
            if (kt2 == 1) {
                // K prefetch next iter (after last St read of kf)
                #pragma unroll
                for (int a = 0; a < 2; ++a)
                    #pragma unroll
                    for (int kd = 0; kd < 4; ++kd)
                        kf[a][kd] = *(const bf16x8*)&kbase[((size_t)itn * 64 + a * 32) * KV * DH + kd * 16];
            }
            // ---- PV half-tile: O += P @ V over keys kt2*32..+31 ----
            __builtin_amdgcn_s_setprio(1);
            #pragma unroll
            for (int dt = 0; dt < 2; ++dt)
                #pragma unroll
                for (int f = 0; f < 2; ++f) {
                    bf16x8 vf = *(const bf16x8*)&VtW[bufo + (dt * 32 + c32) * 64
                                    + ((((kt2 * 4 + f * 2 + hi) ^ (c32 & 7)) << 3))];
                    #pragma unroll
                    for (int qt = 0; qt < 2; ++qt)
                        oacc[qt][dt] = __builtin_amdgcn_mfma_f32_32x32x16_bf16(pf[qt][f], vf, oacc[qt][dt], 0, 0, 0);
                }
            __builtin_amdgcn_s_setprio(0);
        }
    }

    // ---- epilogue: combine hi-halves of rowsums, then key-halves ----
    #pragma unroll
    for (int qt = 0; qt < 2; ++qt) {
        u32x2 e = __builtin_amdgcn_permlane32_swap(__float_as_uint(rsum[qt]),
                                                   __float_as_uint(rsum[qt]), false, false);
        float tot = __uint_as_float(e.x) + __uint_as_float(e.y);
        Rs[w][qt][c32] = tot;   // both hi-lanes write identical value (benign)
    }
    __syncthreads();   // all loops done; waves 0-3's Vt slices dead -> overlay
    float (*Ep)[64][64] = (float (*)[64][64])&Vt[0][0][0][0];   // 64 KB fp32 partials
    if (g == 1) {
        #pragma unroll
        for (int qt = 0; qt < 2; ++qt)
            #pragma unroll
            for (int dt = 0; dt < 2; ++dt) {
                const int d = dt * 32 + c32;
                #pragma unroll
                for (int rr = 0; rr < 4; ++rr) {
                    const int gq = (qt * 8 + 2 * rr + hi) ^ (d & 15);   // 16B-granule swizzle
                    f32x4 val = {oacc[qt][dt][rr * 4 + 0], oacc[qt][dt][rr * 4 + 1],
                                 oacc[qt][dt][rr * 4 + 2], oacc[qt][dt][rr * 4 + 3]};
                    *(f32x4*)&Ep[w - 4][d][gq * 4] = val;
                }
            }
    }
    __syncthreads();
    if (g == 0) {
        #pragma unroll
        for (int qt = 0; qt < 2; ++qt)
            #pragma unroll
            for (int dt = 0; dt < 2; ++dt) {
                const int d = dt * 32 + c32;
                #pragma unroll
                for (int rr = 0; rr < 4; ++rr) {
                    const int gq = (qt * 8 + 2 * rr + hi) ^ (d & 15);
                    f32x4 val = *(const f32x4*)&Ep[w][d][gq * 4];
                    oacc[qt][dt][rr * 4 + 0] += val[0];
                    oacc[qt][dt][rr * 4 + 1] += val[1];
                    oacc[qt][dt][rr * 4 + 2] += val[2];
                    oacc[qt][dt][rr * 4 + 3] += val[3];
                }
            }
        #pragma unroll
        for (int qt = 0; qt < 2; ++qt)
            #pragma unroll
            for (int rr = 0; rr < 4; ++rr) {
                f32x4 ra = *(const f32x4*)&Rs[w][qt][8 * rr + 4 * hi];
                f32x4 rb = *(const f32x4*)&Rs[w + 4][qt][8 * rr + 4 * hi];
                #pragma unroll
                for (int i = 0; i < 4; ++i) {
                    float inv = 1.0f / (ra[i] + rb[i]);
                    int row = q0 + qt * 32 + 8 * rr + 4 * hi + i;
                    #pragma unroll
                    for (int dt = 0; dt < 2; ++dt)
                        ob[(size_t)row * (H * DH) + h * DH + dt * 32 + c32] =
                            f2bf(oacc[qt][dt][rr * 4 + i] * inv);
                }
            }
    }
}

// ---------------------------------------------------------------------------
extern "C" void kernel_launch(void* const* d_in, const int* in_sizes, int n_in,
                              void* d_out, int out_size, void* d_ws, size_t ws_size,
                              hipStream_t stream) {
    const float* x  = (const float*)d_in[0];
    const float* Wq = (const float*)d_in[1];
    const float* Wk = (const float*)d_in[2];
    const float* Wv = (const float*)d_in[3];
    const float* Wo = (const float*)d_in[4];
    float* out = (float*)d_out;

    // ---- workspace (~26.2 MB) ----
    char* ws = (char*)d_ws;
    unsigned short* xb    = (unsigned short*)ws;                      // 8.39 MB
    unsigned short* ob    = xb;                                       // aliases xb (dead after QKV GEMM)
    unsigned short* qb    = (unsigned short*)(ws + 8388608);          // 8.39 MB
    unsigned short* kb    = (unsigned short*)(ws + 16777216);         // 2.10 MB
    unsigned short* vbT   = (unsigned short*)(ws + 18874368);         // 2.10 MB (V transposed [kv*DH+d][L])
    unsigned short* WqkvT = (unsigned short*)(ws + 20971520);         // 3.15 MB
    unsigned short* WoT   = (unsigned short*)(ws + 24117248);         // 2.10 MB

    dim3 blk(256);

    // 1) convert + transpose everything
    prep_kernel<<<6656, blk, 0, stream>>>(x, Wq, Wk, Wv, Wo, xb, WqkvT, WoT);

    // 2) fused QKV projection + RoPE + bf16 pack (V written transposed)
    gemm_qkv_rope<<<dim3(12, 64), blk, 0, stream>>>(xb, WqkvT, qb, kb, vbT);

    // 3) attention (barrier-free main loop, wave-private V staging)
    attn_mfma_kernel<<<dim3(L / 64, KV), dim3(512), 0, stream>>>(qb, kb, vbT, ob);

    // 4) output projection (64x128 tiles, 512 blocks)
    gemm_bf16<<<dim3(D / 128, L / 64), blk, 0, stream>>>(ob, WoT, out, L, D, D);
}

// Round 13
// 212.372 us; speedup vs baseline: 1.0294x; 1.0294x over previous
//
#include <hip/hip_runtime.h>
#include <math.h>

#define L 4096
#define D 1024
#define H 16
#define KV 4
#define DH 64
// G = H/KV = 4

typedef __attribute__((ext_vector_type(8))) short bf16x8;
typedef __attribute__((ext_vector_type(4))) float f32x4;
typedef __attribute__((ext_vector_type(16))) float f32x16;
typedef __attribute__((ext_vector_type(2))) unsigned int u32x2;

static __device__ __forceinline__ unsigned short f2bf(float f) {
    unsigned u = __float_as_uint(f);
    u = (u + 0x7FFF + ((u >> 16) & 1)) >> 16;   // RNE
    return (unsigned short)u;
}

static __device__ __forceinline__ bf16x8 mk8(unsigned a, unsigned b, unsigned c, unsigned d) {
    union { unsigned u[4]; bf16x8 v; } x;
    x.u[0] = a; x.u[1] = b; x.u[2] = c; x.u[3] = d;
    return x.v;
}

#define EXP2F(x) __builtin_amdgcn_exp2f(x)
#define ZERO16 ((f32x16){0.f,0.f,0.f,0.f,0.f,0.f,0.f,0.f,0.f,0.f,0.f,0.f,0.f,0.f,0.f,0.f})

// async global->LDS, 16B per lane; dst must be wave-uniform base (HW: base + lane*16)
#define GLD16(src, dst) \
    __builtin_amdgcn_global_load_lds((__attribute__((address_space(1))) void*)(src), \
                                     (__attribute__((address_space(3))) void*)(dst), 16, 0, 0)

// ---------------------------------------------------------------------------
// prep: x fp32->bf16, and the four weight transposes (dst[n][k] bf16, K=1024).
// ---------------------------------------------------------------------------
__global__ __launch_bounds__(256) void prep_kernel(
        const float* __restrict__ x,  const float* __restrict__ Wq,
        const float* __restrict__ Wk, const float* __restrict__ Wv,
        const float* __restrict__ Wo,
        unsigned short* __restrict__ xb, unsigned short* __restrict__ WqkvT,
        unsigned short* __restrict__ WoT) {
    const int b = blockIdx.x, tid = threadIdx.x;
    if (b < 4096) {
        int i = (b * 256 + tid) * 4;
        float4 v = *(const float4*)&x[i];
        ushort4 o;
        o.x = f2bf(v.x); o.y = f2bf(v.y); o.z = f2bf(v.z); o.w = f2bf(v.w);
        *(ushort4*)&xb[i] = o;
        return;
    }
    __shared__ float t[32][33];
    const float* src; unsigned short* dst; int N, n0, k0;
    if (b < 5120)      { int tq = b - 4096; src = Wq; dst = WqkvT;                     N = 1024; n0 = (tq & 31) * 32; k0 = (tq >> 5) * 32; }
    else if (b < 5376) { int tq = b - 5120; src = Wk; dst = WqkvT + (size_t)1024*1024; N = 256;  n0 = (tq & 7)  * 32; k0 = (tq >> 3) * 32; }
    else if (b < 5632) { int tq = b - 5376; src = Wv; dst = WqkvT + (size_t)1280*1024; N = 256;  n0 = (tq & 7)  * 32; k0 = (tq >> 3) * 32; }
    else               { int tq = b - 5632; src = Wo; dst = WoT;                       N = 1024; n0 = (tq & 31) * 32; k0 = (tq >> 5) * 32; }
    const int tx = tid & 31, ty = tid >> 5;
    #pragma unroll
    for (int j = 0; j < 4; ++j)
        t[ty + 8 * j][tx] = src[(size_t)(k0 + ty + 8 * j) * N + n0 + tx];
    __syncthreads();
    #pragma unroll
    for (int j = 0; j < 4; ++j)
        dst[(size_t)(n0 + ty + 8 * j) * 1024 + k0 + tx] = f2bf(t[tx][ty + 8 * j]);
}

// ---------------------------------------------------------------------------
// bf16 MFMA GEMM (fp32 out) for the Wo projection. Tile 64x128, 512 blocks.
// ---------------------------------------------------------------------------
__global__ __launch_bounds__(256) void gemm_bf16(const unsigned short* __restrict__ A,
                                                 const unsigned short* __restrict__ BT,
                                                 float* __restrict__ C,
                                                 int M, int N, int K) {
    __shared__ unsigned short As[64 * 32];
    __shared__ unsigned short Bs[128 * 32];

    const int tid  = threadIdx.x;
    const int w    = tid >> 6;
    const int lane = tid & 63;
    const int c    = lane & 15;
    const int quad = lane >> 4;
    const int wy = w >> 1, wx = w & 1;
    const int row0 = blockIdx.y * 64;
    const int col0 = blockIdx.x * 128;

    const int ld_row = lane >> 2;
    const int ld_col = (lane & 3) * 8;

    f32x4 acc[2][4];
    #pragma unroll
    for (int mt = 0; mt < 2; ++mt)
        #pragma unroll
        for (int nt = 0; nt < 4; ++nt)
            acc[mt][nt] = (f32x4){0.f, 0.f, 0.f, 0.f};

    for (int k0 = 0; k0 < K; k0 += 32) {
        __syncthreads();
        GLD16(&A [(size_t)(row0 + w * 16 + ld_row)      * K + k0 + ld_col], &As[w * 512]);
        GLD16(&BT[(size_t)(col0 + w * 16 + ld_row)      * K + k0 + ld_col], &Bs[w * 512]);
        GLD16(&BT[(size_t)(col0 + w * 16 + 64 + ld_row) * K + k0 + ld_col], &Bs[w * 512 + 2048]);
        __syncthreads();

        bf16x8 af[2], bfr[4];
        #pragma unroll
        for (int mt = 0; mt < 2; ++mt)
            af[mt] = *(const bf16x8*)&As[(wy * 32 + mt * 16 + c) * 32 + quad * 8];
        #pragma unroll
        for (int nt = 0; nt < 4; ++nt)
            bfr[nt] = *(const bf16x8*)&Bs[(wx * 64 + nt * 16 + c) * 32 + quad * 8];

        #pragma unroll
        for (int mt = 0; mt < 2; ++mt)
            #pragma unroll
            for (int nt = 0; nt < 4; ++nt)
                acc[mt][nt] = __builtin_amdgcn_mfma_f32_16x16x32_bf16(af[mt], bfr[nt], acc[mt][nt], 0, 0, 0);
    }

    #pragma unroll
    for (int mt = 0; mt < 2; ++mt)
        #pragma unroll
        for (int nt = 0; nt < 4; ++nt)
            #pragma unroll
            for (int r = 0; r < 4; ++r)
                C[(size_t)(row0 + wy * 32 + mt * 16 + quad * 4 + r) * N
                  + col0 + wx * 64 + nt * 16 + c] = acc[mt][nt][r];
}

// ---------------------------------------------------------------------------
// Fused QKV GEMM + RoPE epilogue. Tile 64x128, grid (12,64) = 768 blocks.
// K is written PER-HEAD CONTIGUOUS (kb[kv][l][DH], 128B rows) and V
// TRANSPOSED (vbT[kv*DH+d][l]) so attention can stage BOTH via coalesced
// global_load_lds (R12 post-mortem: the 512B-strided K gather was ~2300
// scattered L2 transactions per CU-iteration — the real attn limiter).
// ---------------------------------------------------------------------------
__global__ __launch_bounds__(256) void gemm_qkv_rope(
        const unsigned short* __restrict__ A,
        const unsigned short* __restrict__ BT,
        unsigned short* __restrict__ qb,
        unsigned short* __restrict__ kbuf,
        unsigned short* __restrict__ vbT) {
    __shared__ unsigned short As[64 * 32];
    __shared__ unsigned short Bs[128 * 32];

    const int tid  = threadIdx.x;
    const int w    = tid >> 6;
    const int lane = tid & 63;
    const int c    = lane & 15;
    const int quad = lane >> 4;
    const int wy = w >> 1, wx = w & 1;
    const int row0 = blockIdx.y * 64;
    const int col0 = blockIdx.x * 128;

    const int ld_row = lane >> 2;
    const int ld_col = (lane & 3) * 8;

    f32x4 acc[2][4];
    #pragma unroll
    for (int mt = 0; mt < 2; ++mt)
        #pragma unroll
        for (int nt = 0; nt < 4; ++nt)
            acc[mt][nt] = (f32x4){0.f, 0.f, 0.f, 0.f};

    for (int k0 = 0; k0 < 1024; k0 += 32) {
        __syncthreads();
        GLD16(&A [(size_t)(row0 + w * 16 + ld_row)      * 1024 + k0 + ld_col], &As[w * 512]);
        GLD16(&BT[(size_t)(col0 + w * 16 + ld_row)      * 1024 + k0 + ld_col], &Bs[w * 512]);
        GLD16(&BT[(size_t)(col0 + w * 16 + 64 + ld_row) * 1024 + k0 + ld_col], &Bs[w * 512 + 2048]);
        __syncthreads();

        bf16x8 af[2], bfr[4];
        #pragma unroll
        for (int mt = 0; mt < 2; ++mt)
            af[mt] = *(const bf16x8*)&As[(wy * 32 + mt * 16 + c) * 32 + quad * 8];
        #pragma unroll
        for (int nt = 0; nt < 4; ++nt)
            bfr[nt] = *(const bf16x8*)&Bs[(wx * 64 + nt * 16 + c) * 32 + quad * 8];

        #pragma unroll
        for (int mt = 0; mt < 2; ++mt)
            #pragma unroll
            for (int nt = 0; nt < 4; ++nt)
                acc[mt][nt] = __builtin_amdgcn_mfma_f32_16x16x32_bf16(af[mt], bfr[nt], acc[mt][nt], 0, 0, 0);
    }

    const int colb = col0 + wx * 64;
    if (colb < 1280) {
        unsigned short* dst; size_t ls, hs; int hh; float scale;
        if (colb < 1024) { dst = qb;   ls = H * DH; hs = DH;            hh = colb >> 6;          scale = 0.18033688011112042f; }
        else             { dst = kbuf; ls = DH;     hs = (size_t)L * DH; hh = (colb - 1024) >> 6; scale = 1.0f; }
        #pragma unroll
        for (int nt = 0; nt < 2; ++nt) {
            int d = nt * 16 + c;
            float invf = EXP2F((float)d * -0.4152410118609203f);
            #pragma unroll
            for (int mt = 0; mt < 2; ++mt)
                #pragma unroll
                for (int r = 0; r < 4; ++r) {
                    int l = row0 + wy * 32 + mt * 16 + quad * 4 + r;
                    float ang = (float)l * invf;
                    float sn = __sinf(ang), cs = __cosf(ang);
                    float x1 = acc[mt][nt][r], x2 = acc[mt][nt + 2][r];
                    dst[(size_t)l * ls + (size_t)hh * hs + d]      = f2bf((x1 * cs - x2 * sn) * scale);
                    dst[(size_t)l * ls + (size_t)hh * hs + d + 32] = f2bf((x2 * cs + x1 * sn) * scale);
                }
        }
    } else {
        // V^T: vbT[(vh*DH + d) * L + l], packed 4 contiguous l per store
        int vh = (colb - 1280) >> 6;
        #pragma unroll
        for (int nt = 0; nt < 4; ++nt)
            #pragma unroll
            for (int mt = 0; mt < 2; ++mt) {
                int l = row0 + wy * 32 + mt * 16 + quad * 4;
                ushort4 o;
                o.x = f2bf(acc[mt][nt][0]); o.y = f2bf(acc[mt][nt][1]);
                o.z = f2bf(acc[mt][nt][2]); o.w = f2bf(acc[mt][nt][3]);
                *(ushort4*)&vbT[(size_t)(vh * DH + nt * 16 + c) * L + l] = o;
            }
    }
}

// ---------------------------------------------------------------------------
// MFMA attention, 32x32x16 — FULLY-COALESCED staging of K AND V via
// global_load_lds. Grid (64, KV), 512 thr, 1 block/CU, 2 waves/SIMD.
// Wave w: head kv*4+(w&3), key-half g=w>>2, 64 q-rows, 32 iters of 64 keys.
//
// R12 post-mortem: barrier removal was neutral -> limiter is the scattered
// K gather (8 loads x 32 cache lines each, ~2300 L2 transactions/CU-iter
// through the TA). Fix: K now per-head contiguous (kb[kv][l][DH]), so each
// group's 64x64 K tile and V^T tile stage as 8+8 coalesced GLD16 (4/wave,
// source pre-swizzled chunk^=row&7, linear LDS dest). Global transactions
// per CU-iter: ~2300 scattered -> 32 coalesced. kf becomes ds_read_b128
// from LDS (granule^=key&7 -> ~2 lanes/bank, free), mid-loop K prefetch
// gone. One barrier/iter (R3-proven) drains both stagings.
// LDS: Tiles[K/V][group][buf][64][64] = 64 KB + Rs 2 KB; fp32 epilogue
// partials overlay the dead Tiles.
// Softmax fully in-register; rowsums = VALU adds on bf16-truncated values.
// NOTE (R2): plain loop body only — no [&] lambda. NOTE (R10): 1024-thr
// blocks force a 64-VGPR binary; stay at 512 thr.
// ---------------------------------------------------------------------------
__global__ __attribute__((amdgpu_flat_work_group_size(512, 512), amdgpu_waves_per_eu(2)))
void attn_mfma_kernel(
        const unsigned short* __restrict__ qb,
        const unsigned short* __restrict__ kb,    // [kv][l][DH]
        const unsigned short* __restrict__ vbT,   // [kv*DH + d][l]
        unsigned short* __restrict__ ob) {
    __shared__ __align__(16) unsigned short Tiles[2][2][2][64][64];  // 64 KB [K/V][grp][buf][row][64]
    __shared__ __align__(16) float Rs[8][2][32];                     //  2 KB rowsums [wave][qt][q]

    const int tid  = threadIdx.x;
    const int w    = tid >> 6;        // 0..7
    const int lane = tid & 63;
    const int c32  = lane & 31;
    const int hi   = lane >> 5;
    const int g    = w >> 2;          // key group
    const int kv = blockIdx.y;
    const int h  = kv * 4 + (w & 3);
    const int q0 = blockIdx.x * 64;
    const int s_base = g * 2048;

    // ---- staging geometry: slab s covers rows s*8..s*8+7 of a [64][64]
    // tile; lane l loads row lr8=l>>3, source 16B-chunk (l&7)^lr8 (lands at
    // phys chunk l&7 -> LDS holds logical chunk c at phys c^(row&7)).
    // Wave sw=w&3 stages K slabs {2sw,2sw+1} and V slabs {2sw,2sw+1}.
    const int sw  = w & 3;
    const int lr8 = lane >> 3, lc8 = lane & 7;
    const unsigned short* kstage = kb  + ((size_t)kv * L + s_base + lr8) * DH + ((lc8 ^ lr8) << 3);
    const unsigned short* vstage = vbT + ((size_t)kv * DH + lr8) * L + s_base + ((lc8 ^ lr8) << 3);
    unsigned short* KtB = &Tiles[0][g][0][0][0];
    unsigned short* VtB = &Tiles[1][g][0][0][0];

    // Q B-frags: col=q=c32, k-elems d = kd*16 + hi*8 + j
    bf16x8 qf[2][4];
    {
        const unsigned short* qbase = qb + ((size_t)(q0 + c32) * H + h) * DH + hi * 8;
        #pragma unroll
        for (int qt = 0; qt < 2; ++qt)
            #pragma unroll
            for (int kd = 0; kd < 4; ++kd)
                qf[qt][kd] = *(const bf16x8*)&qbase[qt * 32 * H * DH + kd * 16];
    }

    f32x16 oacc[2][2];    // [qt][dt]: col=d=dt*32+c32, row=q=(r&3)+8(r>>2)+4hi
    #pragma unroll
    for (int qt = 0; qt < 2; ++qt)
        #pragma unroll
        for (int dt = 0; dt < 2; ++dt)
            oacc[qt][dt] = ZERO16;
    float rsum[2] = {0.f, 0.f};   // per-lane partial rowsum, q = qt*32 + c32

    // ---- prologue: stage tile 0 into buf 0 (4 coalesced GLD16 per wave) ----
    GLD16(kstage + (size_t)(2 * sw)     * 8 * DH, KtB + (2 * sw)     * 512);
    GLD16(kstage + (size_t)(2 * sw + 1) * 8 * DH, KtB + (2 * sw + 1) * 512);
    GLD16(vstage + (size_t)(2 * sw)     * 8 * L,  VtB + (2 * sw)     * 512);
    GLD16(vstage + (size_t)(2 * sw + 1) * 8 * L,  VtB + (2 * sw + 1) * 512);

    for (int it = 0; it < 32; ++it) {
        const int bufo = (it & 1) * 4096;    // elems; [buf] stride in Tiles
        __syncthreads();   // drains own GLD16s (vmcnt 0 before barrier) -> buf staged; buf^1 reads done

        if (it != 31) {    // stage next tile into buf^1 (async, overlaps compute)
            const int nb = bufo ^ 4096;
            const size_t ko = (size_t)(it + 1) * 64 * DH;
            const int    vo = (it + 1) * 64;
            GLD16(kstage + ko + (size_t)(2 * sw)     * 8 * DH, KtB + nb + (2 * sw)     * 512);
            GLD16(kstage + ko + (size_t)(2 * sw + 1) * 8 * DH, KtB + nb + (2 * sw + 1) * 512);
            GLD16(vstage + vo + (size_t)(2 * sw)     * 8 * L,  VtB + nb + (2 * sw)     * 512);
            GLD16(vstage + vo + (size_t)(2 * sw + 1) * 8 * L,  VtB + nb + (2 * sw + 1) * 512);
        }

        #pragma unroll
        for (int kt2 = 0; kt2 < 2; ++kt2) {
            // K A-frags from LDS: key=kt2*32+c32, granule 2kd+hi (^ key&7)
            bf16x8 kfr[4];
            #pragma unroll
            for (int kd = 0; kd < 4; ++kd)
                kfr[kd] = *(const bf16x8*)&KtB[bufo + (kt2 * 32 + c32) * 64
                                + (((2 * kd + hi) ^ (c32 & 7)) << 3)];

            bf16x8 pf[2][2];   // [qt][f]: PV A-frags, keys kt2*32 + f*16 + hi*8 + j
            #pragma unroll
            for (int qt = 0; qt < 2; ++qt) {
                // St = K @ Q^T (32x32, K-dim = DH via 4 chained MFMAs)
                f32x16 s = ZERO16;
                #pragma unroll
                for (int kd = 0; kd < 4; ++kd)
                    s = __builtin_amdgcn_mfma_f32_32x32x16_bf16(kfr[kd], qf[qt][kd], s, 0, 0, 0);
                // exp2, truncate to bf16 domain (matches packed PV operand)
                float p[16];
                #pragma unroll
                for (int r = 0; r < 16; ++r)
                    p[r] = __uint_as_float(__float_as_uint(EXP2F(s[r])) & 0xFFFF0000u);
                // rowsum for q = qt*32+c32 over this lane's 16 keys
                float t0 = (p[0] + p[1]) + (p[2] + p[3]);
                float t1 = (p[4] + p[5]) + (p[6] + p[7]);
                float t2 = (p[8] + p[9]) + (p[10] + p[11]);
                float t3 = (p[12] + p[13]) + (p[14] + p[15]);
                rsum[qt] += (t0 + t1) + (t2 + t3);
                // pack key-pairs: u[i] = bf16(p[2i]) | bf16(p[2i+1])<<16
                unsigned u[8];
                #pragma unroll
                for (int i = 0; i < 8; ++i)
                    u[i] = __builtin_amdgcn_perm(__float_as_uint(p[2 * i + 1]),
                                                 __float_as_uint(p[2 * i]), 0x07060302u);
                // cross-half redistribute: swap(u0,u2)->slots{0,2}, swap(u1,u3)->slots{1,3}
                #pragma unroll
                for (int f = 0; f < 2; ++f) {
                    u32x2 e0 = __builtin_amdgcn_permlane32_swap(u[4 * f + 0], u[4 * f + 2], false, false);
                    u32x2 e1 = __builtin_amdgcn_permlane32_swap(u[4 * f + 1], u[4 * f + 3], false, false);
                    pf[qt][f] = mk8(e0.x, e1.x, e0.y, e1.y);
                }
            }
            // ---- PV half-tile: O += P @ V over keys kt2*32..+31 ----
            __builtin_amdgcn_s_setprio(1);
            #pragma unroll
            for (int dt = 0; dt < 2; ++dt)
                #pragma unroll
                for (int f = 0; f < 2; ++f) {
                    bf16x8 vf = *(const bf16x8*)&VtB[bufo + (dt * 32 + c32) * 64
                                    + ((((kt2 * 4 + f * 2 + hi) ^ (c32 & 7)) << 3))];
                    #pragma unroll
                    for (int qt = 0; qt < 2; ++qt)
                        oacc[qt][dt] = __builtin_amdgcn_mfma_f32_32x32x16_bf16(pf[qt][f], vf, oacc[qt][dt], 0, 0, 0);
                }
            __builtin_amdgcn_s_setprio(0);
        }
    }

    // ---- epilogue: combine hi-halves of rowsums, then key-halves ----
    #pragma unroll
    for (int qt = 0; qt < 2; ++qt) {
        u32x2 e = __builtin_amdgcn_permlane32_swap(__float_as_uint(rsum[qt]),
                                                   __float_as_uint(rsum[qt]), false, false);
        float tot = __uint_as_float(e.x) + __uint_as_float(e.y);
        Rs[w][qt][c32] = tot;   // both hi-lanes write identical value (benign)
    }
    __syncthreads();   // all loop reads done; Tiles dead -> overlay
    float (*Ep)[64][64] = (float (*)[64][64])&Tiles[0][0][0][0][0];   // 64 KB fp32 partials
    if (g == 1) {
        #pragma unroll
        for (int qt = 0; qt < 2; ++qt)
            #pragma unroll
            for (int dt = 0; dt < 2; ++dt) {
                const int d = dt * 32 + c32;
                #pragma unroll
                for (int rr = 0; rr < 4; ++rr) {
                    const int gq = (qt * 8 + 2 * rr + hi) ^ (d & 15);   // 16B-granule swizzle
                    f32x4 val = {oacc[qt][dt][rr * 4 + 0], oacc[qt][dt][rr * 4 + 1],
                                 oacc[qt][dt][rr * 4 + 2], oacc[qt][dt][rr * 4 + 3]};
                    *(f32x4*)&Ep[w - 4][d][gq * 4] = val;
                }
            }
    }
    __syncthreads();
    if (g == 0) {
        #pragma unroll
        for (int qt = 0; qt < 2; ++qt)
            #pragma unroll
            for (int dt = 0; dt < 2; ++dt) {
                const int d = dt * 32 + c32;
                #pragma unroll
                for (int rr = 0; rr < 4; ++rr) {
                    const int gq = (qt * 8 + 2 * rr + hi) ^ (d & 15);
                    f32x4 val = *(const f32x4*)&Ep[w][d][gq * 4];
                    oacc[qt][dt][rr * 4 + 0] += val[0];
                    oacc[qt][dt][rr * 4 + 1] += val[1];
                    oacc[qt][dt][rr * 4 + 2] += val[2];
                    oacc[qt][dt][rr * 4 + 3] += val[3];
                }
            }
        #pragma unroll
        for (int qt = 0; qt < 2; ++qt)
            #pragma unroll
            for (int rr = 0; rr < 4; ++rr) {
                f32x4 ra = *(const f32x4*)&Rs[w][qt][8 * rr + 4 * hi];
                f32x4 rb = *(const f32x4*)&Rs[w + 4][qt][8 * rr + 4 * hi];
                #pragma unroll
                for (int i = 0; i < 4; ++i) {
                    float inv = 1.0f / (ra[i] + rb[i]);
                    int row = q0 + qt * 32 + 8 * rr + 4 * hi + i;
                    #pragma unroll
                    for (int dt = 0; dt < 2; ++dt)
                        ob[(size_t)row * (H * DH) + h * DH + dt * 32 + c32] =
                            f2bf(oacc[qt][dt][rr * 4 + i] * inv);
                }
            }
    }
}

// ---------------------------------------------------------------------------
extern "C" void kernel_launch(void* const* d_in, const int* in_sizes, int n_in,
                              void* d_out, int out_size, void* d_ws, size_t ws_size,
                              hipStream_t stream) {
    const float* x  = (const float*)d_in[0];
    const float* Wq = (const float*)d_in[1];
    const float* Wk = (const float*)d_in[2];
    const float* Wv = (const float*)d_in[3];
    const float* Wo = (const float*)d_in[4];
    float* out = (float*)d_out;

    // ---- workspace (~26.2 MB) ----
    char* ws = (char*)d_ws;
    unsigned short* xb    = (unsigned short*)ws;                      // 8.39 MB
    unsigned short* ob    = xb;                                       // aliases xb (dead after QKV GEMM)
    unsigned short* qb    = (unsigned short*)(ws + 8388608);          // 8.39 MB
    unsigned short* kb    = (unsigned short*)(ws + 16777216);         // 2.10 MB (K per-head contiguous [kv][l][DH])
    unsigned short* vbT   = (unsigned short*)(ws + 18874368);         // 2.10 MB (V transposed [kv*DH+d][L])
    unsigned short* WqkvT = (unsigned short*)(ws + 20971520);         // 3.15 MB
    unsigned short* WoT   = (unsigned short*)(ws + 24117248);         // 2.10 MB

    dim3 blk(256);

    // 1) convert + transpose everything
    prep_kernel<<<6656, blk, 0, stream>>>(x, Wq, Wk, Wv, Wo, xb, WqkvT, WoT);

    // 2) fused QKV projection + RoPE + bf16 pack (K per-head, V transposed)
    gemm_qkv_rope<<<dim3(12, 64), blk, 0, stream>>>(xb, WqkvT, qb, kb, vbT);

    // 3) attention (coalesced K+V staging, 1 barrier/iter)
    attn_mfma_kernel<<<dim3(L / 64, KV), dim3(512), 0, stream>>>(qb, kb, vbT, ob);

    // 4) output projection (64x128 tiles, 512 blocks)
    gemm_bf16<<<dim3(D / 128, L / 64), blk, 0, stream>>>(ob, WoT, out, L, D, D);
}